// Round 5
// baseline (318.918 us; speedup 1.0000x reference)
//
#include <hip/hip_runtime.h>

#define HH 448
#define WW 608
#define CC 64
#define S1 32
#define S2 16
#define HW (HH * WW)
#define BLK 640

// No LDS, no barriers. w2/w3 per-pixel matrices are gathered straight from
// global memory: each row's w2 slice is 128 KB (L2-resident after first touch),
// and the 4 float4 quads of one (k1, c) w2 row share a single 128 B cache line,
// so same-k1 lanes coalesce in L1. x is re-read per stage in 32-channel chunks
// (row slice = 155 KB, L2-resident) so only stage 1 ever holds all 64 channels.
// VGPR peak ~85 (stage 1) -> fits the 102-reg cap of (640,5): 2 blocks/CU,
// whole 448-block grid co-resident.
//
// NUMERICS: summation orders are verbatim from the passing rounds 1/2 —
// per-class acc = bias, then channels ascending 0..63, argmax ascending with
// strict '>'. Round 3 proved reordering flips near-tie argmaxes. Do not change.

__launch_bounds__(BLK, 5)
__global__ void reg2stage_kernel(const float* __restrict__ x,
                                 const float* __restrict__ w1,
                                 const float* __restrict__ b1,
                                 const float* __restrict__ w2,
                                 const float* __restrict__ b2,
                                 const float* __restrict__ w3,
                                 const float* __restrict__ b3,
                                 float* __restrict__ out) {
    const int h = blockIdx.x;
    const int w = threadIdx.x;
    if (w >= WW) return;            // no barriers -> early exit is safe

    const float* __restrict__ xp = x + (size_t)h * WW + w;

    // ---- stage 1: per-row GEMV + argmax (w1 wave-uniform -> s_loads) ----
    int k1 = 0;
    {
        float xv[CC];
#pragma unroll
        for (int c = 0; c < CC; ++c) xv[c] = xp[(size_t)c * HW];

        const float* __restrict__ w1r = w1 + (size_t)h * (S1 * CC);
        const float* __restrict__ b1r = b1 + (size_t)h * S1;
        float best1 = -INFINITY;
        for (int k = 0; k < S1; ++k) {
            float acc = b1r[k];
            const float* __restrict__ wk = w1r + k * CC;
#pragma unroll
            for (int c = 0; c < CC; ++c) acc += xv[c] * wk[c];
            if (acc > best1) { best1 = acc; k1 = k; }
        }
    }   // xv[64] dies here

    // ---- stage 2: gather w2[h*S1+k1] (C x S2) from global, x in 32-ch chunks ----
    const float* __restrict__ w2k = w2 + ((size_t)h * S1 + k1) * (CC * S2);
    const float* __restrict__ b2k = b2 + ((size_t)h * S1 + k1) * S2;

    float acc2[S2];
#pragma unroll
    for (int q = 0; q < 4; ++q) {
        const float4 bq = reinterpret_cast<const float4*>(b2k)[q];
        acc2[4 * q + 0] = bq.x;
        acc2[4 * q + 1] = bq.y;
        acc2[4 * q + 2] = bq.z;
        acc2[4 * q + 3] = bq.w;
    }
#pragma unroll
    for (int half = 0; half < 2; ++half) {
        float xh[32];
#pragma unroll
        for (int c = 0; c < 32; ++c) xh[c] = xp[(size_t)(half * 32 + c) * HW];
#pragma unroll
        for (int cl = 0; cl < 32; ++cl) {
            const float xc = xh[cl];
            const float4* __restrict__ wrow =
                reinterpret_cast<const float4*>(w2k + (half * 32 + cl) * S2);
#pragma unroll
            for (int q = 0; q < 4; ++q) {
                const float4 v = wrow[q];
                acc2[4 * q + 0] += xc * v.x;
                acc2[4 * q + 1] += xc * v.y;
                acc2[4 * q + 2] += xc * v.z;
                acc2[4 * q + 3] += xc * v.w;
            }
        }
    }

    float best2 = -INFINITY;
    int k2b = 0;
#pragma unroll
    for (int k2 = 0; k2 < S2; ++k2) {
        if (acc2[k2] > best2) { best2 = acc2[k2]; k2b = k2; }
    }

    // ---- stage 3: gather w3[ind2] (C x 2) from global, x in 32-ch chunks ----
    const size_t ind2 = ((size_t)h * S1 + k1) * S2 + k2b;
    const float4* __restrict__ w3p =
        reinterpret_cast<const float4*>(w3 + ind2 * (CC * 2));
    float r0 = b3[ind2 * 2];
    float r1 = b3[ind2 * 2 + 1];
#pragma unroll
    for (int half = 0; half < 2; ++half) {
        float xh[32];
#pragma unroll
        for (int c = 0; c < 32; ++c) xh[c] = xp[(size_t)(half * 32 + c) * HW];
#pragma unroll
        for (int j = 0; j < 16; ++j) {          // channel pair (2j, 2j+1) in half
            const float4 q = w3p[half * 16 + j];
            r0 += xh[2 * j] * q.x + xh[2 * j + 1] * q.z;
            r1 += xh[2 * j] * q.y + xh[2 * j + 1] * q.w;
        }
    }

    const int loc = k1 * S2 + k2b;              // inds2 - h*S1*S2
    const float x_out = ((float)loc + r0) * 0.5f;
    const float mask = (r1 >= 0.0f) ? r1 : 0.01f * r1;

    out[(size_t)h * WW + w] = x_out;
    out[(size_t)HW + (size_t)h * WW + w] = mask;
}

extern "C" void kernel_launch(void* const* d_in, const int* in_sizes, int n_in,
                              void* d_out, int out_size, void* d_ws, size_t ws_size,
                              hipStream_t stream) {
    const float* x  = (const float*)d_in[0];
    const float* w1 = (const float*)d_in[1];
    const float* b1 = (const float*)d_in[2];
    const float* w2 = (const float*)d_in[3];
    const float* b2 = (const float*)d_in[4];
    const float* w3 = (const float*)d_in[5];
    const float* b3 = (const float*)d_in[6];
    float* out = (float*)d_out;

    reg2stage_kernel<<<dim3(HH), dim3(BLK), 0, stream>>>(x, w1, b1, w2, b2, w3, b3, out);
}

// Round 6
// 116.804 us; speedup vs baseline: 2.7304x; 2.7304x over previous
//
#include <hip/hip_runtime.h>

#define HH 448
#define WW 608
#define CC 64
#define S1 32
#define S2 16
#define HW (HH * WW)
#define BLK 640
#define NCH 4096   // float4 chunks per 32-channel half: 32 classes * 32 ch * 16 k2 / 4

typedef __attribute__((address_space(1))) const void* gp1_t;
typedef __attribute__((address_space(3))) void* lp3_t;

// LDS layout (per 32-channel half, 64KB):
//   element (k, cl, k2) at word  k*512 + (cl ^ ((k>>2)&1))*16 + 4*((k2>>2) ^ (k&3)) + (k2&3)
// Staged via global_load_lds(16B): LDS dest linear in chunk index, permutation applied
// to the per-lane GLOBAL source address (m173 pattern). Proven correct in round 4.
// Read conflicts: k1 spreads over 8 b128 bank-slots (max possible with linear dest),
// ~3.4-way avg -> ~1.6x LDS service. Accepted.
//
// NO __launch_bounds__ waves-per-eu arg: (640,5) empirically caps VGPR at 48 -> total
// spill (rounds 4/5: WRITE_SIZE 137-147MB). Natural allocation ~90-110, no spill.
__device__ __forceinline__ void stage_chunk(const float* __restrict__ w2row,
                                            float* w2s_base, int i, int hf) {
    const int k   = i >> 7;          // class 0..31
    const int r   = i & 127;
    const int clx = r >> 2;          // swizzled channel-in-half
    const int q2x = r & 3;           // swizzled k2-quad
    const int cl  = clx ^ ((k >> 2) & 1);
    const int c   = hf * 32 + cl;
    const int k2q = q2x ^ (k & 3);
    const int g   = ((k << 6) + c) * 4 + k2q;   // float4 index in w2 row
    __builtin_amdgcn_global_load_lds((gp1_t)(w2row + (size_t)g * 4),
                                     (lp3_t)(w2s_base + (size_t)i * 4),
                                     16, 0, 0);
}

__launch_bounds__(BLK)
__global__ void reg2stage_kernel(const float* __restrict__ x,
                                 const float* __restrict__ w1,
                                 const float* __restrict__ b1,
                                 const float* __restrict__ w2,
                                 const float* __restrict__ b2,
                                 const float* __restrict__ w3,
                                 const float* __restrict__ b3,
                                 float* __restrict__ out) {
    __shared__ float w2s[S1 * 32 * S2];   // 64 KB (one c-half)

    const int h = blockIdx.x;
    const int tid = threadIdx.x;
    const bool active = (tid < WW);
    const int w = tid;

    const float* __restrict__ w2row = w2 + (size_t)h * (S1 * CC * S2);
    const float* __restrict__ xp = x + (size_t)h * WW + w;

    // ---- issue half-0 staging (direct-to-LDS, latency hides under stage 1) ----
#pragma unroll
    for (int j = 0; j < 6; ++j) stage_chunk(w2row, w2s, tid + j * BLK, 0);
    if (tid < NCH - 6 * BLK) stage_chunk(w2row, w2s, 6 * BLK + tid, 0);  // 256-chunk tail

    // ---- stage 1: per-row GEMV + argmax ----
    // NOTE: single sequential FMA chain per class, bias-first, channels ascending,
    // strict '>' argmax — the empirically tie-safe order (rounds 1/2/4). Do not change.
    int k1 = 0;
    if (active) {
        float xv[CC];
#pragma unroll
        for (int c = 0; c < CC; ++c) xv[c] = xp[(size_t)c * HW];

        const float* __restrict__ w1r = w1 + (size_t)h * (S1 * CC);
        const float* __restrict__ b1r = b1 + (size_t)h * S1;
        float best1 = -INFINITY;
        for (int k = 0; k < S1; ++k) {
            float acc = b1r[k];
            const float* __restrict__ wk = w1r + k * CC;
#pragma unroll
            for (int c = 0; c < CC; ++c) acc += xv[c] * wk[c];
            if (acc > best1) { best1 = acc; k1 = k; }
        }
    }   // xv[64] dies here
    __syncthreads();   // drains vmcnt -> half-0 resident

    // ---- stage 2: (C x S2) matvec, LDS half-0 then half-1 ----
    float acc2[S2];
    const int kbase = k1 << 9;                // k1*512
    const int clxor = (k1 >> 2) & 1;
    const int q2xor = k1 & 3;
    if (active) {
        const float* __restrict__ b2k = b2 + ((size_t)h * S1 + k1) * S2;
#pragma unroll
        for (int q = 0; q < 4; ++q) {
            const float4 bq = reinterpret_cast<const float4*>(b2k)[q];
            acc2[4 * q + 0] = bq.x;
            acc2[4 * q + 1] = bq.y;
            acc2[4 * q + 2] = bq.z;
            acc2[4 * q + 3] = bq.w;
        }
        float xh[32];
#pragma unroll
        for (int c = 0; c < 32; ++c) xh[c] = xp[(size_t)c * HW];
#pragma unroll 8
        for (int cl = 0; cl < 32; ++cl) {     // channels 0..31
            const float xc = xh[cl];
            const int rowb = kbase + ((cl ^ clxor) << 4);
#pragma unroll
            for (int q = 0; q < 4; ++q) {
                const float4 v = *reinterpret_cast<const float4*>(
                    &w2s[rowb + ((q ^ q2xor) << 2)]);
                acc2[4 * q + 0] += xc * v.x;
                acc2[4 * q + 1] += xc * v.y;
                acc2[4 * q + 2] += xc * v.z;
                acc2[4 * q + 3] += xc * v.w;
            }
        }
    }
    __syncthreads();   // everyone done reading half-0

    // ---- issue half-1 staging ----
#pragma unroll
    for (int j = 0; j < 6; ++j) stage_chunk(w2row, w2s, tid + j * BLK, 1);
    if (tid < NCH - 6 * BLK) stage_chunk(w2row, w2s, 6 * BLK + tid, 1);
    __syncthreads();   // drains vmcnt -> half-1 resident

    if (!active) return;

    {
        float xh[32];
#pragma unroll
        for (int c = 0; c < 32; ++c) xh[c] = xp[(size_t)(32 + c) * HW];
#pragma unroll 8
        for (int cl = 0; cl < 32; ++cl) {     // channels 32..63
            const float xc = xh[cl];
            const int rowb = kbase + ((cl ^ clxor) << 4);
#pragma unroll
            for (int q = 0; q < 4; ++q) {
                const float4 v = *reinterpret_cast<const float4*>(
                    &w2s[rowb + ((q ^ q2xor) << 2)]);
                acc2[4 * q + 0] += xc * v.x;
                acc2[4 * q + 1] += xc * v.y;
                acc2[4 * q + 2] += xc * v.z;
                acc2[4 * q + 3] += xc * v.w;
            }
        }
    }

    float best2 = -INFINITY;
    int k2b = 0;
#pragma unroll
    for (int k2 = 0; k2 < S2; ++k2) {
        if (acc2[k2] > best2) { best2 = acc2[k2]; k2b = k2; }
    }

    // ---- stage 3: gather w3[ind2] (C x 2) from global, x re-read in halves ----
    const size_t ind2 = ((size_t)h * S1 + k1) * S2 + k2b;
    const float4* __restrict__ w3p =
        reinterpret_cast<const float4*>(w3 + ind2 * (CC * 2));
    float r0 = b3[ind2 * 2];
    float r1 = b3[ind2 * 2 + 1];
#pragma unroll
    for (int half = 0; half < 2; ++half) {
        float xh[32];
#pragma unroll
        for (int c = 0; c < 32; ++c) xh[c] = xp[(size_t)(half * 32 + c) * HW];
#pragma unroll
        for (int j = 0; j < 16; ++j) {        // channel pair (2j, 2j+1) in half
            const float4 q = w3p[half * 16 + j];
            r0 += xh[2 * j] * q.x + xh[2 * j + 1] * q.z;
            r1 += xh[2 * j] * q.y + xh[2 * j + 1] * q.w;
        }
    }

    const int loc = k1 * S2 + k2b;            // inds2 - h*S1*S2
    const float x_out = ((float)loc + r0) * 0.5f;
    const float mask = (r1 >= 0.0f) ? r1 : 0.01f * r1;

    out[(size_t)h * WW + w] = x_out;
    out[(size_t)HW + (size_t)h * WW + w] = mask;
}

extern "C" void kernel_launch(void* const* d_in, const int* in_sizes, int n_in,
                              void* d_out, int out_size, void* d_ws, size_t ws_size,
                              hipStream_t stream) {
    const float* x  = (const float*)d_in[0];
    const float* w1 = (const float*)d_in[1];
    const float* b1 = (const float*)d_in[2];
    const float* w2 = (const float*)d_in[3];
    const float* b2 = (const float*)d_in[4];
    const float* w3 = (const float*)d_in[5];
    const float* b3 = (const float*)d_in[6];
    float* out = (float*)d_out;

    reg2stage_kernel<<<dim3(HH), dim3(BLK), 0, stream>>>(x, w1, b1, w2, b2, w3, b3, out);
}

// Round 7
// 107.437 us; speedup vs baseline: 2.9684x; 1.0872x over previous
//
#include <hip/hip_runtime.h>

#define HH 448
#define WW 608
#define CC 64
#define S1 32
#define S2 16
#define HW (HH * WW)
#define BLK 640
#define W2WORDS (S1 * CC * S2)              // 32768 words = 128 KB
#define STG_FULL (W2WORDS / BLK)            // 51 full rounds
#define STG_TAIL (W2WORDS - STG_FULL * BLK) // 128 remainder

typedef __attribute__((address_space(1))) const void* gp1_t;
typedef __attribute__((address_space(3))) void* lp3_t;

// LDS layout: word(k, c, k2) = c*512 + (k2>>1)*64 + 2*k + (k2&1)
//  == 8B-slot i8(k,c,j8) = (c*8 + j8)*32 + k   (j8 = k2 pair index)
// Stage-2 read: ds_read_b64 at i8 with fixed (c,j8), lanes vary k1
//   -> bank-group = i8 % 16 = k1 % 16 -> at most 2-way (k1, k1+16) = FREE (m136).
//   Same-k1 lanes broadcast. This beats the old 16B-granular staging, whose
//   bank-group had only 8 positions (chunk%8) -> unavoidable 4-way (1.58x).
// Staged via global_load_lds WIDTH 4: LDS dest linear in word index (wave base +
// lane*4), per-lane GLOBAL source carries the permutation (m173 pattern).
__device__ __forceinline__ void stage_word(const float* __restrict__ w2row,
                                           float* w2s_base, int i4) {
    const int i8   = i4 >> 1;
    const int half = i4 & 1;
    const int k    = i8 & 31;
    const int t    = i8 >> 5;        // c*8 + j8
    const int j8   = t & 7;
    const int c    = t >> 3;
    const int g    = k * 1024 + c * 16 + 2 * j8 + half;   // word in global w2 row
    __builtin_amdgcn_global_load_lds((gp1_t)(w2row + g),
                                     (lp3_t)(w2s_base + i4), 4, 0, 0);
}

// NUMERICS (do not change): stage-1 per class = bias first, then channels
// ascending 0..63 in ONE sequential chain; argmax ascending, strict '>'.
// Stage-2 per accumulator: bias init, then one update per channel, c ascending.
// Round 3 proved any re-association flips near-tie argmaxes past threshold.
// ALL register arrays (xv, acc2) are indexed with compile-time constants only
// (full unroll) — runtime indexing sends them to scratch (round-6 spill).

__launch_bounds__(BLK)
__global__ void reg2stage_kernel(const float* __restrict__ x,
                                 const float* __restrict__ w1,
                                 const float* __restrict__ b1,
                                 const float* __restrict__ w2,
                                 const float* __restrict__ b2,
                                 const float* __restrict__ w3,
                                 const float* __restrict__ b3,
                                 float* __restrict__ out) {
    __shared__ float w2s[W2WORDS];   // 128 KB -> 1 block/CU (accepted)

    const int h = blockIdx.x;
    const int tid = threadIdx.x;
    const bool active = (tid < WW);
    const int w = tid;

    const float* __restrict__ w2row = w2 + (size_t)h * W2WORDS;
    const float* __restrict__ xp = x + (size_t)h * WW + w;

    // ---- 1) issue x loads FIRST (oldest in vmcnt queue: stage-1's waits on
    //         them will NOT force the younger staging loads to drain) ----
    float xv[CC];
    if (active) {
#pragma unroll
        for (int c = 0; c < CC; ++c) xv[c] = xp[(size_t)c * HW];
    }

    // ---- 2) issue full 128 KB staging, width-4 direct-to-LDS ----
#pragma unroll
    for (int j = 0; j < STG_FULL; ++j) stage_word(w2row, w2s, tid + j * BLK);
    if (tid < STG_TAIL) stage_word(w2row, w2s, STG_FULL * BLK + tid);

    // ---- 3) stage 1: per-row GEMV + argmax (overlaps staging) ----
    int k1 = 0;
    if (active) {
        const float* __restrict__ w1r = w1 + (size_t)h * (S1 * CC);
        const float* __restrict__ b1r = b1 + (size_t)h * S1;
        float best1 = -INFINITY;
        for (int k = 0; k < S1; ++k) {
            float acc = b1r[k];
            const float* __restrict__ wk = w1r + k * CC;
#pragma unroll
            for (int c = 0; c < CC; ++c) acc += xv[c] * wk[c];
            if (acc > best1) { best1 = acc; k1 = k; }
        }
    }

    __syncthreads();   // drains vmcnt -> all of w2s resident
    if (!active) return;

    // ---- 4) stage 2: (C x S2) matvec from LDS, ds_read_b64, 2-way max ----
    float acc2[S2];
    {
        const float* __restrict__ b2k = b2 + ((size_t)h * S1 + k1) * S2;
#pragma unroll
        for (int q = 0; q < 4; ++q) {
            const float4 bq = reinterpret_cast<const float4*>(b2k)[q];
            acc2[4 * q + 0] = bq.x;
            acc2[4 * q + 1] = bq.y;
            acc2[4 * q + 2] = bq.z;
            acc2[4 * q + 3] = bq.w;
        }
    }
#pragma unroll
    for (int c = 0; c < CC; ++c) {
        const float xc = xv[c];
        const float2* __restrict__ p =
            reinterpret_cast<const float2*>(&w2s[c * 512 + 2 * k1]);
#pragma unroll
        for (int j8 = 0; j8 < 8; ++j8) {
            const float2 v = p[j8 * 32];       // +256 B per j8: imm offset
            acc2[2 * j8 + 0] += xc * v.x;
            acc2[2 * j8 + 1] += xc * v.y;
        }
    }

    float best2 = -INFINITY;
    int k2b = 0;
#pragma unroll
    for (int k2 = 0; k2 < S2; ++k2) {
        if (acc2[k2] > best2) { best2 = acc2[k2]; k2b = k2; }
    }

    // ---- 5) stage 3: (C x 2) matvec gathered from global (L2/L3 resident) ----
    const size_t ind2 = ((size_t)h * S1 + k1) * S2 + k2b;
    const float4* __restrict__ w3p =
        reinterpret_cast<const float4*>(w3 + ind2 * (CC * 2));
    float r0 = b3[ind2 * 2];
    float r1 = b3[ind2 * 2 + 1];
#pragma unroll
    for (int j = 0; j < 32; ++j) {            // channel pair (2j, 2j+1)
        const float4 q = w3p[j];
        r0 += xv[2 * j] * q.x + xv[2 * j + 1] * q.z;
        r1 += xv[2 * j] * q.y + xv[2 * j + 1] * q.w;
    }

    const int loc = k1 * S2 + k2b;            // inds2 - h*S1*S2
    const float x_out = ((float)loc + r0) * 0.5f;
    const float mask = (r1 >= 0.0f) ? r1 : 0.01f * r1;

    out[(size_t)h * WW + w] = x_out;
    out[(size_t)HW + (size_t)h * WW + w] = mask;
}

extern "C" void kernel_launch(void* const* d_in, const int* in_sizes, int n_in,
                              void* d_out, int out_size, void* d_ws, size_t ws_size,
                              hipStream_t stream) {
    const float* x  = (const float*)d_in[0];
    const float* w1 = (const float*)d_in[1];
    const float* b1 = (const float*)d_in[2];
    const float* w2 = (const float*)d_in[3];
    const float* b2 = (const float*)d_in[4];
    const float* w3 = (const float*)d_in[5];
    const float* b3 = (const float*)d_in[6];
    float* out = (float*)d_out;

    reg2stage_kernel<<<dim3(HH), dim3(BLK), 0, stream>>>(x, w1, b1, w2, b2, w3, b3, out);
}

// Round 8
// 91.608 us; speedup vs baseline: 3.4813x; 1.1728x over previous
//
#include <hip/hip_runtime.h>

#define HH 448
#define WW 608
#define CC 64
#define S1 32
#define S2 16
#define HW (HH * WW)
#define BLK 640
#define W2F4 (S1 * CC * S2 / 4)     // 8192 float4 = 128 KB
#define NSTG 13                     // ceil(8192/640); last is partial (512 threads)

// LDS layout: word(k, c, k2) = c*512 + (k2>>1)*64 + ((2k + 4*(c&15)) & 63) + (k2&1)
// Fields are disjoint -> bijective onto [0, 32768).
// READ  (critical path, 512 ds_read_b64/thread): per (c, j8) instr lanes vary k1;
//       bank = (2k1 + 4(c&15)) mod 32 -> distinct for k1 mod 16 -> <=2-way = FREE (m136).
// WRITE (26 ds_write_b64/thread, trivial volume): lanes span 16 c x 4 q -> 8-way
//       (2.94x of ~2cyc on 26 instrs ~ 150 cyc/wave). Accepted.
// GLOBAL staging reads are float4 with consecutive-lane-consecutive-address
// (full coalescing) — this is what round 7's swizzled-source global_load_lds
// destroyed (lanes 4KB apart -> 780 GB/s effective).
//
// ISSUE ORDER: xv loads FIRST (oldest in vmcnt queue), staging second. Stage-1
// waits only on xv -> 13 staging loads stay in flight under ~7us of stage-1
// VALU (counted-vmcnt semantics). Round 2 had stg-first and the compiler
// serialized everything (VGPR=84 proved loads were sunk).
//
// NUMERICS (do not change): stage-1 per class = bias first then channels 0..63
// ascending, ONE sequential chain; stage-2 = bias init then c ascending, k2
// ascending within c; argmax strict '>' ascending. All register arrays fully
// unrolled (compile-time indices only) — runtime indexing spills (round 6).

__launch_bounds__(BLK)
__global__ void reg2stage_kernel(const float* __restrict__ x,
                                 const float* __restrict__ w1,
                                 const float* __restrict__ b1,
                                 const float* __restrict__ w2,
                                 const float* __restrict__ b2,
                                 const float* __restrict__ w3,
                                 const float* __restrict__ b3,
                                 float* __restrict__ out) {
    __shared__ float w2s[S1 * CC * S2];   // 128 KB -> 1 block/CU (VGPR budget 204)

    const int h = blockIdx.x;
    const int tid = threadIdx.x;
    const bool active = (tid < WW);
    const int w = tid;

    const float* __restrict__ xp = x + (size_t)h * WW + w;
    const float4* __restrict__ w2row4 =
        reinterpret_cast<const float4*>(w2 + (size_t)h * (S1 * CC * S2));

    // ---- 1) xv loads first (oldest in vmcnt queue) ----
    float xv[CC];
    if (active) {
#pragma unroll
        for (int c = 0; c < CC; ++c) xv[c] = xp[(size_t)c * HW];
    }

    // ---- 2) staging loads second: perfectly coalesced float4 ----
    float4 stg[NSTG];
#pragma unroll
    for (int i = 0; i < NSTG - 1; ++i) stg[i] = w2row4[tid + i * BLK];
    if (tid < W2F4 - (NSTG - 1) * BLK)            // 512-thread tail round
        stg[NSTG - 1] = w2row4[tid + (NSTG - 1) * BLK];

    // ---- 3) stage 1: per-row GEMV + argmax (staging loads in flight) ----
    int k1 = 0;
    if (active) {
        const float* __restrict__ w1r = w1 + (size_t)h * (S1 * CC);
        const float* __restrict__ b1r = b1 + (size_t)h * S1;
        float best1 = -INFINITY;
        for (int k = 0; k < S1; ++k) {
            float acc = b1r[k];
            const float* __restrict__ wk = w1r + k * CC;
#pragma unroll
            for (int c = 0; c < CC; ++c) acc += xv[c] * wk[c];
            if (acc > best1) { best1 = acc; k1 = k; }
        }
    }

    // ---- 4) write staged w2 to LDS (swizzled word layout) ----
#pragma unroll
    for (int i = 0; i < NSTG; ++i) {
        const int e4 = tid + i * BLK;
        if (i < NSTG - 1 || e4 < W2F4) {
            const int k = e4 >> 8;                // class
            const int c = (e4 >> 2) & 63;         // channel
            const int q = e4 & 3;                 // k2 quad -> j8 = 2q, 2q+1
            const int s = (2 * k + 4 * (c & 15)) & 63;
            float* __restrict__ base = &w2s[c * 512 + s];
            *reinterpret_cast<float2*>(base + (2 * q) * 64) =
                make_float2(stg[i].x, stg[i].y);
            *reinterpret_cast<float2*>(base + (2 * q + 1) * 64) =
                make_float2(stg[i].z, stg[i].w);
        }
    }
    __syncthreads();
    if (!active) return;

    // ---- 5) stage 2: (C x S2) matvec, ds_read_b64, <=2-way banks ----
    float acc2[S2];
    {
        const float* __restrict__ b2k = b2 + ((size_t)h * S1 + k1) * S2;
#pragma unroll
        for (int q = 0; q < 4; ++q) {
            const float4 bq = reinterpret_cast<const float4*>(b2k)[q];
            acc2[4 * q + 0] = bq.x;
            acc2[4 * q + 1] = bq.y;
            acc2[4 * q + 2] = bq.z;
            acc2[4 * q + 3] = bq.w;
        }
    }
    const int k1x2 = 2 * k1;
#pragma unroll
    for (int c = 0; c < CC; ++c) {
        const float xc = xv[c];
        const int sw = (k1x2 + 4 * (c & 15)) & 63;
        const float2* __restrict__ p =
            reinterpret_cast<const float2*>(&w2s[c * 512 + sw]);
#pragma unroll
        for (int j8 = 0; j8 < 8; ++j8) {          // k2 pair (2j8, 2j8+1)
            const float2 v = p[j8 * 32];          // +256 B imm offset per j8
            acc2[2 * j8 + 0] += xc * v.x;
            acc2[2 * j8 + 1] += xc * v.y;
        }
    }

    float best2 = -INFINITY;
    int k2b = 0;
#pragma unroll
    for (int k2 = 0; k2 < S2; ++k2) {
        if (acc2[k2] > best2) { best2 = acc2[k2]; k2b = k2; }
    }

    // ---- 6) stage 3: (C x 2) matvec gathered from global (L2/L3 resident) ----
    const size_t ind2 = ((size_t)h * S1 + k1) * S2 + k2b;
    const float4* __restrict__ w3p =
        reinterpret_cast<const float4*>(w3 + ind2 * (CC * 2));
    float r0 = b3[ind2 * 2];
    float r1 = b3[ind2 * 2 + 1];
#pragma unroll
    for (int j = 0; j < 32; ++j) {                // channel pair (2j, 2j+1)
        const float4 q = w3p[j];
        r0 += xv[2 * j] * q.x + xv[2 * j + 1] * q.z;
        r1 += xv[2 * j] * q.y + xv[2 * j + 1] * q.w;
    }

    const int loc = k1 * S2 + k2b;                // inds2 - h*S1*S2
    const float x_out = ((float)loc + r0) * 0.5f;
    const float mask = (r1 >= 0.0f) ? r1 : 0.01f * r1;

    out[(size_t)h * WW + w] = x_out;
    out[(size_t)HW + (size_t)h * WW + w] = mask;
}

extern "C" void kernel_launch(void* const* d_in, const int* in_sizes, int n_in,
                              void* d_out, int out_size, void* d_ws, size_t ws_size,
                              hipStream_t stream) {
    const float* x  = (const float*)d_in[0];
    const float* w1 = (const float*)d_in[1];
    const float* b1 = (const float*)d_in[2];
    const float* w2 = (const float*)d_in[3];
    const float* b2 = (const float*)d_in[4];
    const float* w3 = (const float*)d_in[5];
    const float* b3 = (const float*)d_in[6];
    float* out = (float*)d_out;

    reg2stage_kernel<<<dim3(HH), dim3(BLK), 0, stream>>>(x, w1, b1, w2, b2, w3, b3, out);
}